// Round 9
// baseline (101.872 us; speedup 1.0000x reference)
//
#include <hip/hip_runtime.h>

// WaveKANLinear: out[n,o] = sum_d mexhat((ln(x)[n,d]-t[o,d])/s[o,d]) * ww[o,d]
//                           + silu(sum_d x[n,d]*bw[o,d])
// N=8192, D=128, O=128, float32 in/out.
// R9: block = 32 rows x 64 outputs. Its 64KB bf16 weight half-table lives in
//     LDS for the whole kernel (kills the 537MB L2 weight stream ~15.6us).
//     4 rows/thread amortizes weight read+unpack over 4 evals. Base matmul is
//     folded through LayerNorm algebra so raw x never hits LDS:
//       sum_d raw*bw = sv*(sum_d xn*bwg - cb_o) + mean*sb_o,
//       bwg=bw/gamma, cb_o=sum beta*bwg, sb_o=sum bw, sv=sqrt(var+eps).
//     Hot loop: 1 ds_read_b64 (weights) + 1 ds_read_b64 broadcast (ln) +
//     11 pk f32 + 4 exp per 4 evals. Barrier-free after one sync.

#define D_DIM 128
#define O_DIM 128
#define ROWS  32     // rows per block
#define BLOCK 512    // 8 waves: lane = o-within-half, wave g = 4-row group
#define OH    64     // outputs per block (o-half)

#define C1     0.72134752f   // 0.5*log2(e); exp(-z^2/2) = exp2(-C1*z^2)
#define SQRT_C 0.84932180f   // sqrt(C1)
#define WWK    1.2023651f    // MEX_C / C1, MEX_C = 2/(sqrt(3)*pi^0.25)
#define LOG2E  1.44269504f

typedef float v2f __attribute__((ext_vector_type(2)));

__device__ __forceinline__ unsigned bf16r(float f) {   // RNE round to bf16 bits
    unsigned u = __float_as_uint(f);
    return (u + 0x7fffu + ((u >> 16) & 1u)) >> 16;
}

// ---- VOP3P packed-fp32 helpers (validated in R8: absmax matched plain path) ----
// u = x * hi(w) - lo(w)
__device__ __forceinline__ v2f pk_fma_xhi_nlo(v2f x, v2f w) {
    v2f d;
    asm("v_pk_fma_f32 %0, %1, %2, %2 op_sel:[0,1,0] op_sel_hi:[1,1,0] neg_lo:[0,0,1] neg_hi:[0,0,1]"
        : "=v"(d) : "v"(x), "v"(w));
    return d;
}
__device__ __forceinline__ v2f pk_mul(v2f a, v2f b) {
    v2f d;
    asm("v_pk_mul_f32 %0, %1, %2" : "=v"(d) : "v"(a), "v"(b));
    return d;
}
// d = q * lo(w) + lo(c)
__device__ __forceinline__ v2f pk_fma_lolo(v2f q, v2f w, v2f c) {
    v2f d;
    asm("v_pk_fma_f32 %0, %1, %2, %3 op_sel:[0,0,0] op_sel_hi:[1,0,0]"
        : "=v"(d) : "v"(q), "v"(w), "v"(c));
    return d;
}
// acc += a * b   (plain packed)
__device__ __forceinline__ void pk_fma_vv(v2f& acc, v2f a, v2f b) {
    asm("v_pk_fma_f32 %0, %1, %2, %0" : "+v"(acc) : "v"(a), "v"(b));
}
// acc += s * hi(w)
__device__ __forceinline__ void pk_fma_acc_hi(v2f& acc, v2f s, v2f w) {
    asm("v_pk_fma_f32 %0, %1, %2, %0 op_sel:[0,1,0] op_sel_hi:[1,1,1]"
        : "+v"(acc) : "v"(s), "v"(w));
}

// Prep1: bf16 table [d][o] uint2 { pack(t*is | is<<16), pack(ww*WWK | bwg<<16) }
__global__ __launch_bounds__(256) void wavekan_prep(
    const float* __restrict__ scale,
    const float* __restrict__ trans,
    const float* __restrict__ ww,
    const float* __restrict__ bw,
    const float* __restrict__ gamma,
    uint2* __restrict__ wsW)
{
    int idx = blockIdx.x * blockDim.x + threadIdx.x;   // = o*128 + d
    if (idx >= O_DIM * D_DIM) return;
    int o = idx >> 7;
    int d = idx & (D_DIM - 1);
    float sc = scale[idx];
    float sp = fmaxf(sc, 0.0f) + log1pf(__expf(-fabsf(sc)));  // stable softplus
    float is2 = SQRT_C / (sp + 0.1f);
    float bwg = bw[idx] / gamma[d];
    uint2 w;
    w.x = bf16r(trans[idx] * is2) | (bf16r(is2) << 16);
    w.y = bf16r(ww[idx] * WWK)    | (bf16r(bwg) << 16);
    wsW[d * O_DIM + o] = w;
}

// Prep2: per-o constants cb_o = sum_d beta*bw/gamma, sb_o = sum_d bw.
__global__ __launch_bounds__(128) void wavekan_prep2(
    const float* __restrict__ bw,
    const float* __restrict__ gamma,
    const float* __restrict__ beta,
    float2* __restrict__ cbsb)
{
    int o = blockIdx.x, t = threadIdx.x;               // 128 blocks x 128 thr
    float b  = bw[o * D_DIM + t];
    float bg = b / gamma[t];
    float cb = beta[t] * bg;
    float sb = b;
    #pragma unroll
    for (int m = 1; m < 64; m <<= 1) {
        cb += __shfl_xor(cb, m, 64);
        sb += __shfl_xor(sb, m, 64);
    }
    __shared__ float2 tmp[2];
    if ((t & 63) == 0) tmp[t >> 6] = make_float2(cb, sb);
    __syncthreads();
    if (t == 0) cbsb[o] = make_float2(tmp[0].x + tmp[1].x, tmp[0].y + tmp[1].y);
}

__global__ __launch_bounds__(BLOCK, 4) void wavekan_main(
    const float* __restrict__ x,
    const uint2* __restrict__ wsW,
    const float2* __restrict__ cbsb,
    const float* __restrict__ gamma,
    const float* __restrict__ beta,
    float* __restrict__ out,
    int N)
{
    __shared__ uint4  s_w4[D_DIM * OH / 2];   // 64 KB: weight half-table
    __shared__ uint2  s_ln2[8 * D_DIM];       // 8 KB: bf16 ln, [g][d] 4 rows/entry
    __shared__ float2 s_mr[ROWS];             // {mean, sqrt(var+eps)} per row

    const int tid  = threadIdx.x;
    const int h    = blockIdx.x & 1;          // o-half
    const int row0 = (blockIdx.x >> 1) * ROWS;

    // ---- stage the o-half of the weight table into LDS (uint4 copies) ----
    const uint4* wsW4 = reinterpret_cast<const uint4*>(wsW);
    #pragma unroll
    for (int k = 0; k < 8; ++k) {
        int flat = tid + k * BLOCK;           // 0..4095
        int d = flat >> 5, z = flat & 31;
        s_w4[flat] = wsW4[d * 64 + h * 32 + z];
    }

    // ---- Phase 1: 32 rows, 16 lanes/row x 8 elems; LayerNorm -> bf16 LDS ----
    {
        const int r  = tid >> 4;              // row 0..31
        const int j  = tid & 15;
        const int d0 = j * 8;
        const int grow = row0 + r;

        float v[8];
        if (grow < N) {
            const float4* p = reinterpret_cast<const float4*>(x + (size_t)grow * D_DIM + d0);
            float4 a = p[0], b4 = p[1];
            v[0]=a.x; v[1]=a.y; v[2]=a.z; v[3]=a.w;
            v[4]=b4.x; v[5]=b4.y; v[6]=b4.z; v[7]=b4.w;
        } else {
            #pragma unroll
            for (int k = 0; k < 8; ++k) v[k] = 0.0f;
        }
        float sum = 0.f, ssq = 0.f;
        #pragma unroll
        for (int k = 0; k < 8; ++k) { sum += v[k]; ssq += v[k] * v[k]; }
        #pragma unroll
        for (int m = 1; m < 16; m <<= 1) {    // reduce within 16-lane row group
            sum += __shfl_xor(sum, m, 64);
            ssq += __shfl_xor(ssq, m, 64);
        }
        const float mean = sum * (1.0f / D_DIM);
        const float var  = ssq * (1.0f / D_DIM) - mean * mean;
        const float rstd = rsqrtf(var + 1e-5f);
        const float sv   = (var + 1e-5f) * rstd;       // sqrt(var+eps)

        const float4* pg = reinterpret_cast<const float4*>(gamma + d0);
        const float4* pb = reinterpret_cast<const float4*>(beta + d0);
        float4 g0 = pg[0], g1 = pg[1], b0 = pb[0], b1 = pb[1];
        float gg[8] = {g0.x,g0.y,g0.z,g0.w,g1.x,g1.y,g1.z,g1.w};
        float bb[8] = {b0.x,b0.y,b0.z,b0.w,b1.x,b1.y,b1.z,b1.w};

        const int gi  = r >> 2;               // group 0..7
        const int sub = r & 3;                // slot within uint2 (4 halfwords)
        unsigned short* sl = reinterpret_cast<unsigned short*>(s_ln2);
        #pragma unroll
        for (int k = 0; k < 8; ++k) {
            float ln = (v[k] - mean) * rstd * gg[k] + bb[k];
            sl[(gi * D_DIM + d0 + k) * 4 + sub] = (unsigned short)bf16r(ln);
        }
        if (j == 0) s_mr[r] = make_float2(mean, sv);
    }
    __syncthreads();   // the ONLY barrier

    // ---- Phase 2: lane = o-within-half, wave g = 4-row group ----
    const int lane = tid & 63;
    const int g    = tid >> 6;                // 0..7, wave-uniform
    const int o    = h * OH + lane;
    const uint2* __restrict__ sw = reinterpret_cast<const uint2*>(s_w4);

    v2f accw01 = {0.f,0.f}, accw23 = {0.f,0.f};
    v2f accb01 = {0.f,0.f}, accb23 = {0.f,0.f};
    const v2f vNegC1 = {-C1, -C1};

    #pragma unroll 4
    for (int d = 0; d < D_DIM; ++d) {
        uint2 wv = sw[d * OH + lane];         // ds_read_b64, conflict-free
        uint2 xv = s_ln2[g * D_DIM + d];      // ds_read_b64 broadcast
        v2f w01, w23, xln01, xln23;
        w01.x   = __uint_as_float(wv.x << 16);          // tis
        w01.y   = __uint_as_float(wv.x & 0xffff0000u);  // isv
        w23.x   = __uint_as_float(wv.y << 16);          // wwk
        w23.y   = __uint_as_float(wv.y & 0xffff0000u);  // bwg
        xln01.x = __uint_as_float(xv.x << 16);
        xln01.y = __uint_as_float(xv.x & 0xffff0000u);
        xln23.x = __uint_as_float(xv.y << 16);
        xln23.y = __uint_as_float(xv.y & 0xffff0000u);

        v2f wc  = pk_mul(w23, vNegC1);        // {-C1*wwk, -C1*bwg} (lo used)
        v2f u01 = pk_fma_xhi_nlo(xln01, w01); // xn*isv - tis
        v2f u23 = pk_fma_xhi_nlo(xln23, w01);
        v2f q01 = pk_mul(u01, u01);
        v2f q23 = pk_mul(u23, u23);
        v2f e01 = {__builtin_amdgcn_exp2f(-q01.x), __builtin_amdgcn_exp2f(-q01.y)};
        v2f e23 = {__builtin_amdgcn_exp2f(-q23.x), __builtin_amdgcn_exp2f(-q23.y)};
        v2f p01 = pk_fma_lolo(q01, w23, wc);  // q*wwk - C1*wwk
        v2f p23 = pk_fma_lolo(q23, w23, wc);
        pk_fma_vv(accw01, p01, e01);
        pk_fma_vv(accw23, p23, e23);
        pk_fma_acc_hi(accb01, xln01, w23);    // += xn * bwg
        pk_fma_acc_hi(accb23, xln23, w23);
    }

    // ---- Epilogue: base = sv*(accb - cb) + mean*sb; out = accw + silu(base) ----
    float2 cs = cbsb[o];
    float aw[4] = {accw01.x, accw01.y, accw23.x, accw23.y};
    float ab[4] = {accb01.x, accb01.y, accb23.x, accb23.y};
    #pragma unroll
    for (int k = 0; k < 4; ++k) {
        const int rr = row0 + g * 4 + k;
        if (rr < N) {
            float2 mr  = s_mr[g * 4 + k];
            float base = (ab[k] - cs.x) * mr.y + mr.x * cs.y;
            float sig  = 1.0f / (1.0f + __builtin_amdgcn_exp2f(-LOG2E * base));
            out[(size_t)rr * O_DIM + o] = aw[k] + base * sig;
        }
    }
}

// Fallback (no workspace): R7-style fp32 path, correctness-only.
__global__ __launch_bounds__(1024, 8) void wavekan_main_fb(
    const float* __restrict__ x,
    const float* __restrict__ scale,
    const float* __restrict__ trans,
    const float* __restrict__ ww,
    const float* __restrict__ bw,
    const float* __restrict__ gamma,
    const float* __restrict__ beta,
    float* __restrict__ out,
    int N)
{
    __shared__ float4 s_x[128 * 9];
    const int tid = threadIdx.x;
    const int row0 = blockIdx.x * 16;
    {
        const int r = tid >> 6, j = tid & 63, d0 = j * 2;
        const int grow = row0 + r;
        float2 v2 = make_float2(0.f, 0.f);
        if (grow < N) v2 = *reinterpret_cast<const float2*>(x + (size_t)grow * D_DIM + d0);
        float sum = v2.x + v2.y, ssq = v2.x * v2.x + v2.y * v2.y;
        #pragma unroll
        for (int m = 1; m < 64; m <<= 1) { sum += __shfl_xor(sum, m, 64); ssq += __shfl_xor(ssq, m, 64); }
        const float mean = sum / 128.f, var = ssq / 128.f - mean * mean;
        const float rstd = rsqrtf(var + 1e-5f);
        float2 g2 = *reinterpret_cast<const float2*>(gamma + d0);
        float2 b2 = *reinterpret_cast<const float2*>(beta + d0);
        const int p = r >> 1, hh = r & 1;
        float* c0 = reinterpret_cast<float*>(&s_x[d0 * 9 + p]);
        float* c1 = reinterpret_cast<float*>(&s_x[(d0 + 1) * 9 + p]);
        c0[hh] = (v2.x - mean) * rstd * g2.x + b2.x; c0[2 + hh] = v2.x;
        c1[hh] = (v2.y - mean) * rstd * g2.y + b2.y; c1[2 + hh] = v2.y;
    }
    __syncthreads();
    const int o = tid & 127, g = tid >> 7;
    float aw0 = 0.f, aw1 = 0.f, ab0 = 0.f, ab1 = 0.f;
    for (int d = 0; d < D_DIM; ++d) {
        int idx = o * D_DIM + d;
        float sc = scale[idx];
        float sp = fmaxf(sc, 0.0f) + log1pf(__expf(-fabsf(sc)));
        float is = SQRT_C / (sp + 0.1f);
        float tws = trans[idx] * is, wwk = ww[idx] * WWK, bwv = bw[idx];
        float4 xx = s_x[d * 9 + g];
        float u0 = fmaf(xx.x, is, -tws), u1 = fmaf(xx.y, is, -tws);
        float q0 = u0 * u0, q1 = u1 * u1;
        aw0 = fmaf((q0 - C1) * __builtin_amdgcn_exp2f(-q0), wwk, aw0);
        aw1 = fmaf((q1 - C1) * __builtin_amdgcn_exp2f(-q1), wwk, aw1);
        ab0 = fmaf(xx.z, bwv, ab0);
        ab1 = fmaf(xx.w, bwv, ab1);
    }
    const int rr0 = row0 + g * 2;
    if (rr0 < N) {
        float s0 = 1.0f / (1.0f + __builtin_amdgcn_exp2f(-LOG2E * ab0));
        out[(size_t)rr0 * O_DIM + o] = aw0 + ab0 * s0;
    }
    if (rr0 + 1 < N) {
        float s1 = 1.0f / (1.0f + __builtin_amdgcn_exp2f(-LOG2E * ab1));
        out[(size_t)(rr0 + 1) * O_DIM + o] = aw1 + ab1 * s1;
    }
}

extern "C" void kernel_launch(void* const* d_in, const int* in_sizes, int n_in,
                              void* d_out, int out_size, void* d_ws, size_t ws_size,
                              hipStream_t stream) {
    const float* x     = (const float*)d_in[0];
    const float* scale = (const float*)d_in[1];
    const float* trans = (const float*)d_in[2];
    const float* ww    = (const float*)d_in[3];
    const float* bw    = (const float*)d_in[4];
    const float* gamma = (const float*)d_in[5];
    const float* beta  = (const float*)d_in[6];
    float* out = (float*)d_out;

    const int N = in_sizes[0] / D_DIM;       // 8192

    const size_t tbl_bytes = (size_t)O_DIM * D_DIM * sizeof(uint2);   // 128 KB
    const size_t ws_needed = tbl_bytes + O_DIM * sizeof(float2);
    if (ws_size >= ws_needed) {
        uint2*  tbl  = (uint2*)d_ws;
        float2* cbsb = (float2*)((char*)d_ws + tbl_bytes);
        wavekan_prep<<<(O_DIM * D_DIM + 255) / 256, 256, 0, stream>>>(
            scale, trans, ww, bw, gamma, tbl);
        wavekan_prep2<<<O_DIM, 128, 0, stream>>>(bw, gamma, beta, cbsb);
        const int grid = ((N + ROWS - 1) / ROWS) * 2;   // 512
        wavekan_main<<<grid, BLOCK, 0, stream>>>(
            x, tbl, cbsb, gamma, beta, out, N);
    } else {
        wavekan_main_fb<<<(N + 15) / 16, 1024, 0, stream>>>(
            x, scale, trans, ww, bw, gamma, beta, out, N);
    }
}